// Round 6
// baseline (551.549 us; speedup 1.0000x reference)
//
#include <hip/hip_runtime.h>
#include <hip/hip_bf16.h>

#define NBLK 256   // build_csr grid size; 256 blocks x 256 thr = guaranteed co-resident on 256 CUs

// ---- device-scope grid barrier (bar[0]=arrive, bar[1]=generation; both zeroed by memset) ----
__device__ __forceinline__ void grid_barrier(int* bar, int nblk) {
    __syncthreads();
    if (threadIdx.x == 0) {
        __threadfence();  // agent-scope release of prior plain stores (L2 writeback)
        int gen = __hip_atomic_load(&bar[1], __ATOMIC_RELAXED, __HIP_MEMORY_SCOPE_AGENT);
        int prev = __hip_atomic_fetch_add(&bar[0], 1, __ATOMIC_ACQ_REL, __HIP_MEMORY_SCOPE_AGENT);
        if (prev == nblk - 1) {
            __hip_atomic_store(&bar[0], 0, __ATOMIC_RELAXED, __HIP_MEMORY_SCOPE_AGENT);
            __hip_atomic_fetch_add(&bar[1], 1, __ATOMIC_RELEASE, __HIP_MEMORY_SCOPE_AGENT);
        } else {
            while (__hip_atomic_load(&bar[1], __ATOMIC_ACQUIRE, __HIP_MEMORY_SCOPE_AGENT) == gen)
                __builtin_amdgcn_s_sleep(8);
        }
    }
    __syncthreads();
}

// ---- fused CSR build: degree histogram -> scan -> dinv/self-loop -> edge fill ----
// cnt[] and bar[] pre-zeroed by one hipMemsetAsync. Requires ceil(N/NBLK) <= 256.
__global__ __launch_bounds__(256) void build_csr(const int* __restrict__ src,
                                                 const int* __restrict__ dst,
                                                 int* cnt, int* rowptr, float* dinv,
                                                 int* col, int* partial, int* bar,
                                                 int N, int E) {
    int t = threadIdx.x;
    // phase 1: degree histogram (device-scope atomics, coherent cross-XCD)
    for (int e = blockIdx.x * 256 + t; e < E; e += NBLK * 256)
        atomicAdd(&cnt[dst[e]], 1);
    grid_barrier(bar, NBLK);

    // phase 2a: per-block chunk scan of (cnt[i]+1)
    int C = (N + NBLK - 1) / NBLK;     // 196 for N=50000
    int base = blockIdx.x * C;
    int i = base + t;
    __shared__ int s[256];
    int v = (t < C && i < N) ? (cnt[i] + 1) : 0;
    s[t] = v;
    __syncthreads();
    for (int off = 1; off < 256; off <<= 1) {
        int x = (t >= off) ? s[t - off] : 0;
        __syncthreads();
        s[t] += x;
        __syncthreads();
    }
    int incl = s[t];                    // inclusive within chunk
    if (t == 255) partial[blockIdx.x] = s[255];
    grid_barrier(bar, NBLK);

    // phase 2b: every block redundantly scans the 256 partials
    __shared__ int p[NBLK];
    p[t] = partial[t];
    __syncthreads();
    for (int off = 1; off < NBLK; off <<= 1) {
        int x = (t >= off) ? p[t - off] : 0;
        __syncthreads();
        p[t] += x;
        __syncthreads();
    }
    int blockPrefix = (blockIdx.x == 0) ? 0 : p[blockIdx.x - 1];

    // phase 2c: rowptr / dinv / self-loop slot
    if (t < C && i < N) {
        int inc = incl + blockPrefix;
        rowptr[i + 1] = inc;
        int c1 = cnt[i] + 1;
        dinv[i] = rsqrtf((float)c1);
        col[inc - c1] = i;              // self-loop occupies slot 0 of row i
    }
    if (blockIdx.x == 0 && t == 0) rowptr[0] = 0;
    grid_barrier(bar, NBLK);

    // phase 3: fill edges; cnt[] (still = deg) reused as cursor via atomicSub:
    // slots rowptr[d]+1 .. rowptr[d]+deg get the real edges.
    for (int e = blockIdx.x * 256 + t; e < E; e += NBLK * 256) {
        int d = dst[e];
        int pos = rowptr[d] + atomicSub(&cnt[d], 1);
        col[pos] = src[e];
    }
}

// ---------------- fp32 GEMM: H[N,128] = (X[N,128] @ W[128,128]) * dscale[row] ----------------
// 128 threads, 64x128 tile, 8x8 outputs/thread (rows {4ty..+3, 32+4ty..+3},
// cols {4tx..+3, 64+4tx..+3}).  64 FMAs per 4 ds_read_b128.  782 blocks -> good balance.
__global__ __launch_bounds__(128) void gemm64(const float* __restrict__ X,
                                              const float* __restrict__ W,
                                              const float* __restrict__ dscale,
                                              float* __restrict__ H, int Nrows) {
    __shared__ __align__(16) float xs[16][68];   // [k][row], +4 pad
    __shared__ __align__(16) float ws[16][128];  // [k][col]
    int tid = threadIdx.x;
    int tx = tid & 15;
    int ty = tid >> 4;        // 0..7
    int row0 = blockIdx.x * 64;
    float acc[8][8] = {};
    for (int k0 = 0; k0 < 128; k0 += 16) {
        {   // stage X tile transposed: 64 rows x 16 k = 256 float4, 2/thread
            int r = tid >> 1;            // 0..63
            int jj = (tid & 1) * 8;      // 0 or 8
            int gr = row0 + r;
            float4 v0 = make_float4(0.f, 0.f, 0.f, 0.f), v1 = v0;
            if (gr < Nrows) {
                v0 = *(const float4*)&X[(size_t)gr * 128 + k0 + jj];
                v1 = *(const float4*)&X[(size_t)gr * 128 + k0 + jj + 4];
            }
            xs[jj + 0][r] = v0.x; xs[jj + 1][r] = v0.y; xs[jj + 2][r] = v0.z; xs[jj + 3][r] = v0.w;
            xs[jj + 4][r] = v1.x; xs[jj + 5][r] = v1.y; xs[jj + 6][r] = v1.z; xs[jj + 7][r] = v1.w;
        }
        {   // stage W tile: 16 k x 128 c = 512 float4, 4/thread
            const float4* Wv = (const float4*)&W[(size_t)k0 * 128];
            float4* wsv = (float4*)&ws[0][0];
            wsv[tid] = Wv[tid];
            wsv[tid + 128] = Wv[tid + 128];
            wsv[tid + 256] = Wv[tid + 256];
            wsv[tid + 384] = Wv[tid + 384];
        }
        __syncthreads();
#pragma unroll
        for (int kk = 0; kk < 16; ++kk) {
            float4 xa = *(float4*)&xs[kk][ty * 4];
            float4 xb = *(float4*)&xs[kk][ty * 4 + 32];
            float4 wa = *(float4*)&ws[kk][tx * 4];
            float4 wb = *(float4*)&ws[kk][tx * 4 + 64];
            float xr[8] = {xa.x, xa.y, xa.z, xa.w, xb.x, xb.y, xb.z, xb.w};
            float wr[8] = {wa.x, wa.y, wa.z, wa.w, wb.x, wb.y, wb.z, wb.w};
#pragma unroll
            for (int ii = 0; ii < 8; ++ii)
#pragma unroll
                for (int jj = 0; jj < 8; ++jj)
                    acc[ii][jj] += xr[ii] * wr[jj];
        }
        __syncthreads();
    }
#pragma unroll
    for (int ii = 0; ii < 8; ++ii) {
        int gr = row0 + ((ii < 4) ? (ty * 4 + ii) : (32 + ty * 4 + ii - 4));
        if (gr < Nrows) {
            float sc = dscale[gr];
            *(float4*)&H[(size_t)gr * 128 + tx * 4] =
                make_float4(acc[ii][0] * sc, acc[ii][1] * sc, acc[ii][2] * sc, acc[ii][3] * sc);
            *(float4*)&H[(size_t)gr * 128 + 64 + tx * 4] =
                make_float4(acc[ii][4] * sc, acc[ii][5] * sc, acc[ii][6] * sc, acc[ii][7] * sc);
        }
    }
}

// ---------------- CSR aggregation: out[n] = relu?(dinv[n]*sum(H'[s]) + b) ----------------
// H' pre-scaled by dinv[row] in the GEMM epilogue.  256 threads = 8 nodes x 32
// lanes (float4/lane).  Unroll-4 -> 4 independent dwordx4 gathers in flight.
__global__ __launch_bounds__(256) void agg_kernel(const float* __restrict__ H,
                                                  const float* __restrict__ dinv,
                                                  const int* __restrict__ rowptr,
                                                  const int* __restrict__ col,
                                                  const float* __restrict__ bias,
                                                  float* __restrict__ out,
                                                  int n, int relu) {
    int node = blockIdx.x * 8 + (threadIdx.x >> 5);
    int t = (threadIdx.x & 31) * 4;
    if (node >= n) return;
    int beg = rowptr[node], end = rowptr[node + 1];
    float ax = 0.f, ay = 0.f, az = 0.f, aw = 0.f;
    int k = beg;
    for (; k + 4 <= end; k += 4) {
        int s0 = col[k], s1 = col[k + 1], s2 = col[k + 2], s3 = col[k + 3];
        float4 h0 = *(const float4*)&H[(size_t)s0 * 128 + t];
        float4 h1 = *(const float4*)&H[(size_t)s1 * 128 + t];
        float4 h2 = *(const float4*)&H[(size_t)s2 * 128 + t];
        float4 h3 = *(const float4*)&H[(size_t)s3 * 128 + t];
        ax += (h0.x + h1.x) + (h2.x + h3.x);
        ay += (h0.y + h1.y) + (h2.y + h3.y);
        az += (h0.z + h1.z) + (h2.z + h3.z);
        aw += (h0.w + h1.w) + (h2.w + h3.w);
    }
    for (; k < end; ++k) {
        float4 h = *(const float4*)&H[(size_t)col[k] * 128 + t];
        ax += h.x; ay += h.y; az += h.z; aw += h.w;
    }
    float dn = dinv[node];
    float4 bv = *(const float4*)&bias[t];
    float4 r = make_float4(ax * dn + bv.x, ay * dn + bv.y,
                           az * dn + bv.z, aw * dn + bv.w);
    if (relu) {
        r.x = fmaxf(r.x, 0.f); r.y = fmaxf(r.y, 0.f);
        r.z = fmaxf(r.z, 0.f); r.w = fmaxf(r.w, 0.f);
    }
    *(float4*)&out[(size_t)node * 128 + t] = r;
}

// ---------------- edge decoder: out[e] = dot(X[u], X[v]) ----------------
// 16 lanes per edge, 8 floats per lane (2x float4) -> 4 gathers in flight/lane.
__global__ __launch_bounds__(256) void decoder(const float* __restrict__ X,
                                               const int* __restrict__ eli,
                                               float* __restrict__ out, int EL) {
    int e = blockIdx.x * 16 + (threadIdx.x >> 4);
    int lane = threadIdx.x & 15;
    if (e >= EL) return;
    int u = eli[e], v = eli[EL + e];
    const float4* Xu = (const float4*)&X[(size_t)u * 128 + lane * 8];
    const float4* Xv = (const float4*)&X[(size_t)v * 128 + lane * 8];
    float4 a0 = Xu[0], a1 = Xu[1];
    float4 b0 = Xv[0], b1 = Xv[1];
    float d = a0.x * b0.x + a0.y * b0.y + a0.z * b0.z + a0.w * b0.w
            + a1.x * b1.x + a1.y * b1.y + a1.z * b1.z + a1.w * b1.w;
#pragma unroll
    for (int off = 8; off > 0; off >>= 1) d += __shfl_xor(d, off);
    if (lane == 0) out[e] = d;
}

extern "C" void kernel_launch(void* const* d_in, const int* in_sizes, int n_in,
                              void* d_out, int out_size, void* d_ws, size_t ws_size,
                              hipStream_t stream) {
    const float* x0 = (const float*)d_in[0];
    const float* W1 = (const float*)d_in[1];
    const float* b1 = (const float*)d_in[2];
    const float* W2 = (const float*)d_in[3];
    const float* b2 = (const float*)d_in[4];
    const float* W3 = (const float*)d_in[5];
    const float* b3 = (const float*)d_in[6];
    const int* ei   = (const int*)d_in[7];
    const int* eli  = (const int*)d_in[8];
    float* out = (float*)d_out;

    const int D = 128;
    const int N  = in_sizes[0] / D;
    const int E  = in_sizes[7] / 2;
    const int EL = in_sizes[8] / 2;

    const int* src = ei;        // edge_index[0]
    const int* dst = ei + E;    // edge_index[1]

    // -------- workspace carve-up (256B aligned) --------
    char* ws = (char*)d_ws;
    size_t off = 0;
    auto alloc = [&](size_t bytes) -> void* {
        off = (off + 255) & ~(size_t)255;
        void* p = ws + off;
        off += bytes;
        return p;
    };
    int*   cnt    = (int*)alloc((size_t)(N + 8) * sizeof(int));  // cnt[N] + bar[2] contiguous
    int*   bar    = cnt + N;
    int*   partial= (int*)alloc(NBLK * sizeof(int));
    int*   rowptr = (int*)alloc((size_t)(N + 1) * sizeof(int));
    float* dinv   = (float*)alloc((size_t)N * sizeof(float));
    int*   col    = (int*)alloc((size_t)(E + N) * sizeof(int));
    float* hbuf   = (float*)alloc((size_t)N * D * sizeof(float));
    float* xbuf   = (float*)alloc((size_t)N * D * sizeof(float));
    (void)ws_size;

    // zero degree counters + barrier state in one shot
    hipMemsetAsync(cnt, 0, (size_t)(N + 8) * sizeof(int), stream);

    // ---- single-kernel CSR build (deg + scan + dinv/self-loop + fill) ----
    build_csr<<<NBLK, 256, 0, stream>>>(src, dst, cnt, rowptr, dinv, col, partial, bar, N, E);

    int gemmGrid = (N + 63) / 64;
    int aggGrid  = (N + 7) / 8;

    // ---- layer 1 ----
    gemm64<<<gemmGrid, 128, 0, stream>>>(x0, W1, dinv, hbuf, N);
    agg_kernel<<<aggGrid, 256, 0, stream>>>(hbuf, dinv, rowptr, col, b1, xbuf, N, 1);
    // ---- layer 2 ----
    gemm64<<<gemmGrid, 128, 0, stream>>>(xbuf, W2, dinv, hbuf, N);
    agg_kernel<<<aggGrid, 256, 0, stream>>>(hbuf, dinv, rowptr, col, b2, xbuf, N, 1);
    // ---- layer 3 ----
    gemm64<<<gemmGrid, 128, 0, stream>>>(xbuf, W3, dinv, hbuf, N);
    agg_kernel<<<aggGrid, 256, 0, stream>>>(hbuf, dinv, rowptr, col, b3, xbuf, N, 0);

    // ---- decoder ----
    decoder<<<(EL + 15) / 16, 256, 0, stream>>>(xbuf, eli, out, EL);
}